// Round 7
// baseline (702.708 us; speedup 1.0000x reference)
//
#include <hip/hip_runtime.h>
#include <hip/hip_bf16.h>
#include <math.h>

// Problem constants
#define B_ 4
#define L_ 4096
#define E_ 1024
#define H_ 16
#define D_ 64
#define M_ (B_*L_)   // 16384 rows

typedef __attribute__((ext_vector_type(8))) short s8;     // 8 bf16 (4 VGPRs)
typedef __attribute__((ext_vector_type(4))) float f4;     // MFMA C/D

// g(x) = (softplus(5x)/5)^2 via HW v_exp/v_log; clamp z<=60 (no overflow).
__device__ __forceinline__ float gfun(float x) {
  float z = fminf(5.0f * x, 60.0f);
  float sp = 0.2f * __logf(1.0f + __expf(z));
  return sp * sp;
}

__device__ __forceinline__ unsigned short f2bf(float v) {
  __hip_bfloat16 h = __float2bfloat16(v);
  return *reinterpret_cast<unsigned short*>(&h);
}
__device__ __forceinline__ float bf2f(unsigned short u) {
  __hip_bfloat16 h = *reinterpret_cast<__hip_bfloat16*>(&u);
  return __bfloat162float(h);
}

// async global->LDS, 16 B per lane
__device__ __forceinline__ void gload16(const void* g, void* l) {
  __builtin_amdgcn_global_load_lds(
      (const __attribute__((address_space(1))) void*)g,
      (__attribute__((address_space(3))) void*)l, 16, 0, 0);
}

// ---------------------------------------------------------------------------
// Prep 1: split x into bf16 hi|lo -> Ah [16384,2048], AND accumulate per-b
// column sums (xsum[b][e]) for the q-global path.  R7: grid 1024 blocks x 256
// thr (16 rows/block) -> 4 blk/CU, 16 waves/CU for latency hiding (was 1
// blk/CU with a 64-deep serial row loop).
// ---------------------------------------------------------------------------
__global__ __launch_bounds__(256) void split_x(
    const float* __restrict__ x, unsigned short* __restrict__ Ah,
    float* __restrict__ xsum)
{
  int blk = blockIdx.x, t = threadIdx.x;
  int r0 = blk * 16, b = r0 >> 12;
  int c4 = t * 4;
  float4 cs = {0.f, 0.f, 0.f, 0.f};
  for (int r = 0; r < 16; ++r) {
    int row = r0 + r;
    float4 x4 = *(const float4*)(x + (size_t)row * E_ + c4);
    ushort4 hi, lo;
    unsigned short h;
    h = f2bf(x4.x); hi.x = h; lo.x = f2bf(x4.x - bf2f(h));
    h = f2bf(x4.y); hi.y = h; lo.y = f2bf(x4.y - bf2f(h));
    h = f2bf(x4.z); hi.z = h; lo.z = f2bf(x4.z - bf2f(h));
    h = f2bf(x4.w); hi.w = h; lo.w = f2bf(x4.w - bf2f(h));
    *(ushort4*)&Ah[(size_t)row * 2048 + c4]        = hi;
    *(ushort4*)&Ah[(size_t)row * 2048 + 1024 + c4] = lo;
    cs.x += x4.x; cs.y += x4.y; cs.z += x4.z; cs.w += x4.w;
  }
  atomicAdd(&xsum[b * E_ + c4 + 0], cs.x);
  atomicAdd(&xsum[b * E_ + c4 + 1], cs.y);
  atomicAdd(&xsum[b * E_ + c4 + 2], cs.z);
  atomicAdd(&xsum[b * E_ + c4 + 3], cs.w);
}

// ---------------------------------------------------------------------------
// Prep 2: transpose + split each W -> Bt[z] [1024,2048] bf16 (hi|lo).
// z==0 blocks also finish qg: qg[b][n] += (sum_k xsum[b][k]*Wq[k][n])/(L*8)
// (+ bq[n]/8 from the k0==0 blocks).  Wq tile already in LDS.
// ---------------------------------------------------------------------------
__global__ __launch_bounds__(256) void split_wT(
    const float* __restrict__ Wq, const float* __restrict__ Wk,
    const float* __restrict__ Wv, const float* __restrict__ bq,
    const float* __restrict__ xsum,
    unsigned short* __restrict__ Bt, float* __restrict__ qg)
{
  int z = blockIdx.z;
  const float* W = (z == 0) ? Wq : (z == 1) ? Wk : Wv;
  __shared__ float tile[32][33];
  int t = threadIdx.x;
  int tx = t & 31, ty = t >> 5;                    // ty 0..7
  int k0 = blockIdx.x * 32, n0 = blockIdx.y * 32;
  #pragma unroll
  for (int i = 0; i < 4; ++i)
    tile[ty + i*8][tx] = W[(size_t)(k0 + ty + i*8) * 1024 + n0 + tx];
  __syncthreads();
  unsigned short* Bz = Bt + (size_t)z * 2097152;
  #pragma unroll
  for (int i = 0; i < 4; ++i) {
    int n = n0 + ty + i*8, kk = k0 + tx;
    float v = tile[tx][ty + i*8];
    unsigned short h = f2bf(v);
    Bz[(size_t)n * 2048 + kk]        = h;
    Bz[(size_t)n * 2048 + 1024 + kk] = f2bf(v - bf2f(h));
  }
  if (z == 0 && t < 128) {
    int n = t & 31, b = t >> 5;
    float dot = 0.f;
    #pragma unroll
    for (int kk = 0; kk < 32; ++kk)
      dot += xsum[b * E_ + k0 + kk] * tile[kk][n];
    float val = dot * (1.0f / (L_ * 8.0f));
    if (k0 == 0) val += bq[n0 + n] * 0.125f;
    atomicAdd(&qg[b * E_ + n0 + n], val);
  }
}

// ---------------------------------------------------------------------------
// Kernel 1: fused QKV, 256x256-tile / BK=64 / 8-wave, R5 schedule (reverted
// from R6 — all-reads-up-front regressed): TWO raw s_barriers per K-tile +
// counted vmcnt (loads interleave MFMA, vmcnt never 0 mid-loop).
//
// Grid: 768 blocks x 512 thr = 1 blk/CU (128 KiB LDS), exactly 3 rounds.
// XCD swizzle: xc = li&7; per-XCD order z-outer (32 blocks = 8 m x 4 n per z)
// so one z's B matrix (4 MB) stays L2-resident while A streams.
//
// LDS (bytes): A0 [0,32K) A1 [32K,64K) B0 [64K,96K) B1 [96K,128K)
// each tile = [256 rows][64 k] bf16, row = 128 B, col-slot (16 B) swizzled by
// slot ^= row&7.  global_load_lds writes linearly -> inverse swizzle applied
// to the per-lane GLOBAL source column; ds_read applies the same XOR (#21).
//
// Tile plan (numerics identical to R2-R6):
//   T1: LDA(0)+LDB(0)+LDB(1) [16 b128] -> lgkm0(own) -> MFMA Q(0,0),Q(0,1)
//   T2: LDA(1) [8 b128] -> BARR(#1) -> lgkm0 -> STAGE_B+STAGE_A(t+2)
//       -> MFMA Q(1,0),Q(1,1) -> vmcnt(8) -> BARR(#2)
// Ledger: prologue B0 A0 B1 A1 (16 loads) -> vmcnt(8) = tile0 landed.
//   end-of-tile vmcnt(8) leaves exactly {B,A}(t+2) in flight.
//   Peeled last two tiles: no stages, vmcnt(0) drains.
// NOTE (CU-level model, R6 post-mortem): per tile the LDS pipe serves
// 192 b128 reads (~2300cy) + 64KB stage writes (~500cy) while each of the 4
// matrix pipes needs only ~620cy -> kernel is LDS-throughput-limited; the
// remaining gap to ~3000cy/tile is barrier/lockstep stall.  Further gains
// need read-redundancy reduction (structural) — parked.
//
// z==1 epilogue: wave tile = 128 rows x one head; logit = qg . k via 4-step
// fr-butterfly; aexp=exp(logit), denom += (fr==0 lanes).
// ---------------------------------------------------------------------------
#define PRIO1() __builtin_amdgcn_s_setprio(1)
#define PRIO0() __builtin_amdgcn_s_setprio(0)
#define BARR() do { asm volatile("" ::: "memory"); \
                    __builtin_amdgcn_s_barrier(); \
                    asm volatile("" ::: "memory"); } while (0)
#define WAITL0() asm volatile("s_waitcnt lgkmcnt(0)" ::: "memory")
#define WAITV(n) asm volatile("s_waitcnt vmcnt(" n ")" ::: "memory")

#define STAGE_A(buf, kofs) do { \
  const unsigned short* g_ = gA + (kofs); \
  char* d_ = dA0 + (buf) * 32768; \
  gload16(g_,          d_); \
  gload16(g_ + 131072, d_ +  8192); \
  gload16(g_ + 262144, d_ + 16384); \
  gload16(g_ + 393216, d_ + 24576); \
} while (0)

#define STAGE_B(buf, kofs) do { \
  const unsigned short* g_ = gB + (kofs); \
  char* d_ = dB0 + (buf) * 32768; \
  gload16(g_,          d_); \
  gload16(g_ + 131072, d_ +  8192); \
  gload16(g_ + 262144, d_ + 16384); \
  gload16(g_ + 393216, d_ + 24576); \
} while (0)

#define LDA(buf, mh) do { \
  const char* p_ = shb + (buf) * 32768 + arow + (mh) * 8192; \
  _Pragma("unroll") \
  for (int ii = 0; ii < 4; ++ii) { \
    aF[ii][0] = *(const s8*)(p_ + ii * 2048 + c0); \
    aF[ii][1] = *(const s8*)(p_ + ii * 2048 + c1); \
  } \
} while (0)

#define LDB(buf, nh) do { \
  const char* p_ = shb + 65536 + (buf) * 32768 + brow + (nh) * 4096; \
  _Pragma("unroll") \
  for (int jj = 0; jj < 2; ++jj) { \
    bF[(nh)*2+jj][0] = *(const s8*)(p_ + jj * 2048 + c0); \
    bF[(nh)*2+jj][1] = *(const s8*)(p_ + jj * 2048 + c1); \
  } \
} while (0)

#define MFMAQ(mh, nh) do { \
  _Pragma("unroll") \
  for (int ii = 0; ii < 4; ++ii) \
    _Pragma("unroll") \
    for (int jj = 0; jj < 2; ++jj) { \
      acc[(mh)*4+ii][(nh)*2+jj] = __builtin_amdgcn_mfma_f32_16x16x32_bf16( \
          aF[ii][0], bF[(nh)*2+jj][0], acc[(mh)*4+ii][(nh)*2+jj], 0, 0, 0); \
      acc[(mh)*4+ii][(nh)*2+jj] = __builtin_amdgcn_mfma_f32_16x16x32_bf16( \
          aF[ii][1], bF[(nh)*2+jj][1], acc[(mh)*4+ii][(nh)*2+jj], 0, 0, 0); \
    } \
} while (0)

// One K-tile in buffer `buf`, 2 barriers total; stages (if doStage) target
// tile kofs pair; vmN = vmcnt immediate (string) at tile end.
#define TILE2(buf, doStage, kB_, kA_, vmN) do { \
  /* T1: A-half0 + both B halves; own-wave wait; first 32 MFMA */ \
  LDA(buf, 0); LDB(buf, 0); LDB(buf, 1); \
  WAITL0(); \
  PRIO1(); MFMAQ(0, 0); MFMAQ(0, 1); PRIO0(); \
  /* T2: A-half1; WAR barrier; stages; last 32 MFMA; counted vmcnt; barrier */ \
  LDA(buf, 1); \
  BARR(); \
  WAITL0(); \
  if (doStage) { STAGE_B(buf, kB_); STAGE_A(buf, kA_); } \
  PRIO1(); MFMAQ(1, 0); MFMAQ(1, 1); PRIO0(); \
  WAITV(vmN); \
  BARR(); \
} while (0)

__global__ __launch_bounds__(512, 2) void qkv_mfma(
    const unsigned short* __restrict__ Ah, const unsigned short* __restrict__ Bt,
    const float* __restrict__ bq, const float* __restrict__ bk,
    const float* __restrict__ bv, const float* __restrict__ qg,
    float* __restrict__ aexp, float* __restrict__ denom,
    float* __restrict__ qo, float* __restrict__ ko, float* __restrict__ vo)
{
  __shared__ unsigned short sh[65536];   // 128 KiB

  const int t  = threadIdx.x;
  const int li = blockIdx.x;            // 0..767
  const int xc = li & 7;
  const int idx = li >> 3;              // 0..95 within XCD
  const int z   = idx >> 5;             // 0..2 (z-outer per XCD)
  const int rem = idx & 31;
  const int bm = (xc * 8 + (rem >> 2)) * 256;
  const int bn = (rem & 3) * 256;

  const float* bias = (z == 0) ? bq : (z == 1) ? bk : bv;
  float* out = (z == 0) ? qo : (z == 1) ? ko : vo;
  const unsigned short* Bz = Bt + (size_t)z * 2097152;

  // staging: thread t writes LDS bytes [region + t*16); physical (row,slot) =
  // (t>>3 + 64*ld, t&7).  Source column is the inverse-swizzled slot.
  const int srow = t >> 3;
  const int scol = ((t & 7) ^ (srow & 7)) * 8;        // elements
  const unsigned short* gA = Ah + (size_t)(bm + srow) * 2048 + scol;
  const unsigned short* gB = Bz + (size_t)(bn + srow) * 2048 + scol;
  char* const shb = (char*)sh;
  char* const dA0 = shb +         t * 16;
  char* const dB0 = shb + 65536 + t * 16;

  // compute mapping: 8 waves = 2M x 4N, wave tile 128x64
  const int lane = t & 63, wid = t >> 6;
  const int wm = wid >> 2, wn = wid & 3;
  const int fr = lane & 15, fq = lane >> 4;
  const int c0 = ((fq)     ^ (fr & 7)) * 16;          // kk=0 swizzled col byte
  const int c1 = ((fq + 4) ^ (fr & 7)) * 16;          // kk=1
  const int arow = (wm * 128 + fr) * 128;
  const int brow = (wn *  64 + fr) * 128;

  f4 acc[8][4] = {};
  s8 aF[4][2], bF[4][2];

  // prologue: tiles 0 (buf0) and 1 (buf1)
  STAGE_B(0, 0);  STAGE_A(0, 0);
  STAGE_B(1, 64); STAGE_A(1, 64);
  WAITV("8");
  BARR();

  // K' = 3072 = 48 tiles of 64; seg map: A cols [hi,hi,lo], B cols [hi,lo,hi]
  #pragma unroll 1
  for (int it = 0; it < 23; ++it) {
    const int t2 = 2 * it + 2, t3 = 2 * it + 3;
    const int kA2 = (t2 < 16) ? t2 * 64 : t2 * 64 - 1024;
    const int kB2 = (t2 < 32) ? t2 * 64 : t2 * 64 - 2048;
    const int kA3 = (t3 < 16) ? t3 * 64 : t3 * 64 - 1024;
    const int kB3 = (t3 < 32) ? t3 * 64 : t3 * 64 - 2048;
    TILE2(0, true, kB2, kA2, "8");
    TILE2(1, true, kB3, kA3, "8");
  }
  // peeled final iteration: tiles 46, 47 — no stages, drain
  TILE2(0, false, 0, 0, "0");
  TILE2(1, false, 0, 0, "0");

  // epilogue: C += bias, store
  float bv4[4];
  #pragma unroll
  for (int j = 0; j < 4; ++j) bv4[j] = bias[bn + wn * 64 + j * 16 + fr];
  #pragma unroll
  for (int i = 0; i < 8; ++i) {
    const int mrow = bm + wm * 128 + i * 16 + fq * 4;
    #pragma unroll
    for (int j = 0; j < 4; ++j) {
      const int ncol = bn + wn * 64 + j * 16 + fr;
      #pragma unroll
      for (int r = 0; r < 4; ++r)
        out[(size_t)(mrow + r) * E_ + ncol] = acc[i][j][r] + bv4[j];
    }
  }

  if (z == 1) {
    // alpha epilogue: this wave's 128 rows x head (bn>>6)+wn
    const int b_ = bm >> 12;
    const int h  = (bn >> 6) + wn;
    const int bh = b_ * 16 + h;
    float qgv[4];
    #pragma unroll
    for (int j = 0; j < 4; ++j) qgv[j] = qg[bh * 64 + j * 16 + fr];
    float partial[8][4];
    #pragma unroll
    for (int i = 0; i < 8; ++i)
      #pragma unroll
      for (int r = 0; r < 4; ++r) {
        float p = 0.f;
        #pragma unroll
        for (int j = 0; j < 4; ++j)
          p += qgv[j] * (acc[i][j][r] + bv4[j]);
        p += __shfl_xor(p, 1);
        p += __shfl_xor(p, 2);
        p += __shfl_xor(p, 4);
        p += __shfl_xor(p, 8);
        partial[i][r] = p;
      }
    if (fr == 0) {
      const int lbase = (bm & 4095) + wm * 128 + fq * 4;
      float s = 0.f;
      #pragma unroll
      for (int i = 0; i < 8; ++i)
        #pragma unroll
        for (int r = 0; r < 4; ++r) {
          float e = __expf(partial[i][r]);
          aexp[(size_t)bh * 4096 + lbase + i * 16 + r] = e;
          s += e;
        }
      atomicAdd(&denom[bh], s);
    }
  }
}

// ---------------------------------------------------------------------------
// Kernel 2: KV-state partials, no atomics.
// grid (64 bh, 16 chunks of 256 l); 2 l-teams x (16 d-groups x 8 v-groups);
// 4d x 8v register tile per thread.  Double-buffered 12 KB tiles -> ONE
// __syncthreads per 16-row step; global loads for step i+1 hide under step
// i's FMA block (ping-pong WAR safe by the single barrier).
// ---------------------------------------------------------------------------
__global__ __launch_bounds__(256) void state_part(
    const float* __restrict__ k, const float* __restrict__ v,
    const float* __restrict__ aexp, const float* __restrict__ denom,
    float* __restrict__ Spart, float* __restrict__ SMpart,
    float* __restrict__ kpart, float* __restrict__ kmpart)
{
  int bh = blockIdx.x; int b = bh >> 4, h = bh & 15;
  int c = blockIdx.y;
  int l0 = c * 256;
  float scale = (float)L_ / denom[bh];
  __shared__ float gk[2][16][64], gmk[2][16][64], vt[2][16][64];
  int t = threadIdx.x;
  int lr = t >> 4, cc = (t & 15) * 4;                   // staging role
  int vg = (t & 7) * 8, dg = ((t >> 3) & 15) * 4, team = t >> 7;
  float acc[4][8] = {}, accm[4][8] = {};
  float sgk[4] = {}, sgmk[4] = {};

  for (int lt = 0; lt < 256; lt += 16) {
    int cur = (lt >> 4) & 1;
    int l = l0 + lt + lr;
    size_t off = (size_t)(b*L_ + l) * E_ + h*64 + cc;
    float4 k4 = *(const float4*)(k + off);
    float4 v4 = *(const float4*)(v + off);
    float av = aexp[(size_t)bh * L_ + l] * scale;
    float4 g4, m4;
    g4.x = gfun( k4.x*av); m4.x = gfun(-k4.x*av);
    g4.y = gfun( k4.y*av); m4.y = gfun(-k4.y*av);
    g4.z = gfun( k4.z*av); m4.z = gfun(-k4.z*av);
    g4.w = gfun( k4.w*av); m4.w = gfun(-k4.w*av);
    *(float4*)&gk [cur][lr][cc] = g4;
    *(float4*)&gmk[cur][lr][cc] = m4;
    *(float4*)&vt [cur][lr][cc] = v4;
    __syncthreads();
    #pragma unroll
    for (int l2 = 0; l2 < 8; ++l2) {
      int ls = team * 8 + l2;
      float4 ga = *(float4*)&gk [cur][ls][dg];
      float4 ma = *(float4*)&gmk[cur][ls][dg];
      float4 vA = *(float4*)&vt [cur][ls][vg];
      float4 vB = *(float4*)&vt [cur][ls][vg + 4];
      float gv[4] = {ga.x, ga.y, ga.z, ga.w};
      float mv[4] = {ma.x, ma.y, ma.z, ma.w};
      float vv[8] = {vA.x, vA.y, vA.z, vA.w, vB.x, vB.y, vB.z, vB.w};
      if ((t & 7) == 0) {
        #pragma unroll
        for (int i = 0; i < 4; ++i) { sgk[i] += gv[i]; sgmk[i] += mv[i]; }
      }
      #pragma unroll
      for (int i = 0; i < 4; ++i)
        #pragma unroll
        for (int j = 0; j < 8; ++j) {
          acc [i][j] += gv[i] * vv[j];
          accm[i][j] += mv[i] * vv[j];
        }
    }
  }

  int p = c * 2 + team;                       // 0..31
  size_t pb = ((size_t)(p*64 + bh)) * 4096 + (size_t)dg * 64 + vg;
  #pragma unroll
  for (int i = 0; i < 4; ++i) {
    *(float4*)&Spart [pb + i*64]     = *(float4*)&acc [i][0];
    *(float4*)&Spart [pb + i*64 + 4] = *(float4*)&acc [i][4];
    *(float4*)&SMpart[pb + i*64]     = *(float4*)&accm[i][0];
    *(float4*)&SMpart[pb + i*64 + 4] = *(float4*)&accm[i][4];
  }
  if ((t & 7) == 0) {
    #pragma unroll
    for (int i = 0; i < 4; ++i) {
      kpart [(p*64 + bh)*64 + dg + i] = sgk[i];
      kmpart[(p*64 + bh)*64 + dg + i] = sgmk[i];
    }
  }
}

// ---------------------------------------------------------------------------
// Kernel 3: reduce 32 partials (deterministic).  grid (64 bh, 4 segs).
// ---------------------------------------------------------------------------
__global__ __launch_bounds__(256) void state_reduce(
    const float* __restrict__ Spart, const float* __restrict__ SMpart,
    const float* __restrict__ kpart, const float* __restrict__ kmpart,
    float* __restrict__ S, float* __restrict__ Sm,
    float* __restrict__ ksum, float* __restrict__ kmsum)
{
  int bh = blockIdx.x, seg = blockIdx.y, t = threadIdx.x;
  int idx = seg * 1024 + t * 4;
  float4 s = {0,0,0,0}, sm = {0,0,0,0};
  #pragma unroll
  for (int p = 0; p < 32; ++p) {
    float4 a = *(const float4*)&Spart [((size_t)(p*64 + bh))*4096 + idx];
    float4 c = *(const float4*)&SMpart[((size_t)(p*64 + bh))*4096 + idx];
    s.x += a.x; s.y += a.y; s.z += a.z; s.w += a.w;
    sm.x += c.x; sm.y += c.y; sm.z += c.z; sm.w += c.w;
  }
  *(float4*)&S [(size_t)bh*4096 + idx] = s;
  *(float4*)&Sm[(size_t)bh*4096 + idx] = sm;
  if (seg == 0 && t < 64) {
    float a = 0.f, c = 0.f;
    #pragma unroll
    for (int p = 0; p < 32; ++p) {
      a += kpart [(p*64 + bh)*64 + t];
      c += kmpart[(p*64 + bh)*64 + t];
    }
    ksum [bh*64 + t] = a;
    kmsum[bh*64 + t] = c;
  }
}

// ---------------------------------------------------------------------------
// Kernel 4: output.  R7: 256 threads (was 128): 32 l-groups x 8 v-groups,
// 2l x 8v tile per thread -> 4 waves/block, 4 blk/CU (32 KB LDS) = 4
// waves/SIMD (was 2).  Per-output kk-order unchanged -> out bitwise
// identical.  S/Sm read from GLOBAL in-loop (L1-resident per bh).
// ---------------------------------------------------------------------------
__global__ __launch_bounds__(256, 4) void out_kernel(
    const float* __restrict__ q,
    const float* __restrict__ S, const float* __restrict__ Sm,
    const float* __restrict__ ksum, const float* __restrict__ kmsum,
    float* __restrict__ out)
{
  int bh = blockIdx.x; int b = bh >> 4, h = bh & 15;
  int l0 = blockIdx.y * 64;
  __shared__ float Gq[64][64], Gm[64][64];   // [dd][l]
  int t = threadIdx.x;

  // q -> gfun -> transposed LDS.  lr=t>>2 (row), dq=(t&3)*16 (col quarter).
  int lr = t >> 2, dq = (t & 3) * 16;
  const float4* qp = (const float4*)(q + (size_t)(b*L_ + l0 + lr)*E_ + h*64 + dq);
  #pragma unroll
  for (int j = 0; j < 4; ++j) {
    float4 qv = qp[j];
    float vals[4] = {qv.x, qv.y, qv.z, qv.w};
    #pragma unroll
    for (int jj = 0; jj < 4; ++jj) {
      int dd = dq + j*4 + jj;
      Gq[dd][lr] = gfun(vals[jj]);
      Gm[dd][lr] = gfun(-vals[jj]);
    }
  }
  __syncthreads();

  int tn = (t & 7) * 8, tm = (t >> 3) * 2;
  const float* Sp   = S  + (size_t)bh*4096;
  const float* Smp  = Sm + (size_t)bh*4096;
  const float* ksp  = ksum  + bh*64;
  const float* kmsp = kmsum + bh*64;
  float acc[2][8] = {};
  float den[2] = {};
  #pragma unroll 2
  for (int kk = 0; kk < 64; ++kk) {
    float2 ga = *(const float2*)&Gq[kk][tm];
    float2 ma = *(const float2*)&Gm[kk][tm];
    float4 s0 = *(const float4*)&Sp [kk*64 + tn];
    float4 s1 = *(const float4*)&Sp [kk*64 + tn + 4];
    float4 m0 = *(const float4*)&Smp[kk*64 + tn];
    float4 m1 = *(const float4*)&Smp[kk*64 + tn + 4];
    float ksv = ksp[kk], kmv = kmsp[kk];
    float gv[2] = {ga.x, ga.y};
    float mv[2] = {ma.x, ma.y};
    float sv[8] = {s0.x, s0.y, s0.z, s0.w, s1.x, s1.y, s1.z, s1.w};
    float smv[8] = {m0.x, m0.y, m0.z, m0.w, m1.x, m1.y, m1.z, m1.w};
    #pragma unroll
    for (int i = 0; i < 2; ++i) {
      #pragma unroll
      for (int j = 0; j < 8; ++j)
        acc[i][j] += gv[i]*sv[j] + mv[i]*smv[j];
      den[i] += gv[i]*ksv + mv[i]*kmv;
    }
  }

  #pragma unroll
  for (int i = 0; i < 2; ++i) {
    float r = 1.0f / (den[i] + 1e-6f);
    float4 o0, o1;
    o0.x = acc[i][0]*r; o0.y = acc[i][1]*r; o0.z = acc[i][2]*r; o0.w = acc[i][3]*r;
    o1.x = acc[i][4]*r; o1.y = acc[i][5]*r; o1.z = acc[i][6]*r; o1.w = acc[i][7]*r;
    size_t ro = (size_t)(b*L_ + l0 + tm + i)*E_ + h*64 + tn;
    *(float4*)(out + ro)     = o0;
    *(float4*)(out + ro + 4) = o1;
  }
}

// ---------------------------------------------------------------------------
// Workspace layout (float units):
//   q      : 0          (+16,777,216)
//   k      : 16,777,216 (+16,777,216)
//   qg     : 33,554,432 (+4096)  \
//   denom  : 33,558,528 (+64)     | zeroed by one hipMemsetAsync (8256 fl)
//   xsum   : 33,558,592 (+4096)  /
//   S      : 33,562,688 (+262,144)
//   Sm     : 33,824,832 (+262,144)
//   ksum   : 34,086,976 (+4096)
//   kmsum  : 34,091,072 (+4096)
//   aexp   : 34,095,168 (+262,144)
//   Ah     : f-off 34,357,312 (ushort 33,554,432 = 16,777,216 fl)
//   Bt     : f-off 51,134,528 (ushort  6,291,456 =  3,145,728 fl)
//   end 54,280,256 fl = 217.1 MB
//   Overlays (dead after qkv_mfma): Spart @34,357,312 (+8,388,608),
//   SMpart @42,745,920 (+8,388,608) [= Ah region exactly], kpart @51,134,528
//   (+131,072), kmpart @51,265,600 (+131,072) [inside Bt region].
//   v lives in d_out (consumed by state_part, overwritten by out_kernel).
// ---------------------------------------------------------------------------
extern "C" void kernel_launch(void* const* d_in, const int* in_sizes, int n_in,
                              void* d_out, int out_size, void* d_ws, size_t ws_size,
                              hipStream_t stream) {
  const float* x  = (const float*)d_in[0];
  const float* Wq = (const float*)d_in[1];
  const float* bq = (const float*)d_in[2];
  const float* Wk = (const float*)d_in[3];
  const float* bk = (const float*)d_in[4];
  const float* Wv = (const float*)d_in[5];
  const float* bv = (const float*)d_in[6];
  float* out = (float*)d_out;
  float* ws  = (float*)d_ws;

  float* q      = ws;
  float* k      = ws + 16777216;
  float* qg     = ws + 33554432;
  float* denom  = ws + 33558528;
  float* xsum   = ws + 33558592;
  float* S      = ws + 33562688;
  float* Sm     = ws + 33824832;
  float* ksum   = ws + 34086976;
  float* kmsum  = ws + 34091072;
  float* aexp   = ws + 34095168;
  unsigned short* Ah = (unsigned short*)(ws + 34357312);
  unsigned short* Bt = (unsigned short*)(ws + 51134528);
  float* Spart  = ws + 34357312;   // overlays Ah (dead after qkv_mfma)
  float* SMpart = ws + 42745920;
  float* kpart  = ws + 51134528;   // overlays Bt (dead after qkv_mfma)
  float* kmpart = ws + 51265600;
  float* v      = out;

  hipMemsetAsync(qg, 0, 8256 * sizeof(float), stream);

  split_x<<<1024, 256, 0, stream>>>(x, Ah, xsum);
  split_wT<<<dim3(32, 32, 3), 256, 0, stream>>>(Wq, Wk, Wv, bq, xsum, Bt, qg);
  qkv_mfma<<<dim3(768), 512, 0, stream>>>(Ah, Bt, bq, bk, bv, qg,
                                          aexp, denom, q, k, v);
  state_part<<<dim3(B_*H_, 16), 256, 0, stream>>>(k, v, aexp, denom,
                                                  Spart, SMpart, kpart, kmpart);
  state_reduce<<<dim3(B_*H_, 4), 256, 0, stream>>>(Spart, SMpart, kpart, kmpart,
                                                   S, Sm, ksum, kmsum);
  out_kernel<<<dim3(B_*H_, 64), 256, 0, stream>>>(q, S, Sm, ksum, kmsum, out);
}

// Round 8
// 620.429 us; speedup vs baseline: 1.1326x; 1.1326x over previous
//
#include <hip/hip_runtime.h>
#include <hip/hip_bf16.h>
#include <math.h>

// Problem constants
#define B_ 4
#define L_ 4096
#define E_ 1024
#define H_ 16
#define D_ 64
#define M_ (B_*L_)   // 16384 rows

typedef __attribute__((ext_vector_type(8))) short s8;     // 8 bf16 (4 VGPRs)
typedef __attribute__((ext_vector_type(4))) float f4;     // MFMA C/D

// g(x) = (softplus(5x)/5)^2 via HW v_exp/v_log; clamp z<=60 (no overflow).
__device__ __forceinline__ float gfun(float x) {
  float z = fminf(5.0f * x, 60.0f);
  float sp = 0.2f * __logf(1.0f + __expf(z));
  return sp * sp;
}

__device__ __forceinline__ unsigned short f2bf(float v) {
  __hip_bfloat16 h = __float2bfloat16(v);
  return *reinterpret_cast<unsigned short*>(&h);
}
__device__ __forceinline__ float bf2f(unsigned short u) {
  __hip_bfloat16 h = *reinterpret_cast<__hip_bfloat16*>(&u);
  return __bfloat162float(h);
}

// async global->LDS, 16 B per lane
__device__ __forceinline__ void gload16(const void* g, void* l) {
  __builtin_amdgcn_global_load_lds(
      (const __attribute__((address_space(1))) void*)g,
      (__attribute__((address_space(3))) void*)l, 16, 0, 0);
}

// ---------------------------------------------------------------------------
// Prep 1 (R5 version — R7's 1024-block variant regressed via 4x xsum atomic
// traffic): split x into bf16 hi|lo -> Ah [16384,2048] + per-b column sums.
// grid 256 blocks x 256 thr; block = 64 rows of one b.
// ---------------------------------------------------------------------------
__global__ __launch_bounds__(256) void split_x(
    const float* __restrict__ x, unsigned short* __restrict__ Ah,
    float* __restrict__ xsum)
{
  int blk = blockIdx.x, t = threadIdx.x;
  int r0 = blk * 64, b = r0 >> 12;
  int c4 = t * 4;
  float4 cs = {0.f, 0.f, 0.f, 0.f};
  for (int r = 0; r < 64; ++r) {
    int row = r0 + r;
    float4 x4 = *(const float4*)(x + (size_t)row * E_ + c4);
    ushort4 hi, lo;
    unsigned short h;
    h = f2bf(x4.x); hi.x = h; lo.x = f2bf(x4.x - bf2f(h));
    h = f2bf(x4.y); hi.y = h; lo.y = f2bf(x4.y - bf2f(h));
    h = f2bf(x4.z); hi.z = h; lo.z = f2bf(x4.z - bf2f(h));
    h = f2bf(x4.w); hi.w = h; lo.w = f2bf(x4.w - bf2f(h));
    *(ushort4*)&Ah[(size_t)row * 2048 + c4]        = hi;
    *(ushort4*)&Ah[(size_t)row * 2048 + 1024 + c4] = lo;
    cs.x += x4.x; cs.y += x4.y; cs.z += x4.z; cs.w += x4.w;
  }
  atomicAdd(&xsum[b * E_ + c4 + 0], cs.x);
  atomicAdd(&xsum[b * E_ + c4 + 1], cs.y);
  atomicAdd(&xsum[b * E_ + c4 + 2], cs.z);
  atomicAdd(&xsum[b * E_ + c4 + 3], cs.w);
}

// ---------------------------------------------------------------------------
// Prep 2: transpose + split each W -> Bt[z] [1024,2048] bf16 (hi|lo).
// z==0 blocks also finish qg: qg[b][n] += (sum_k xsum[b][k]*Wq[k][n])/(L*8)
// (+ bq[n]/8 from the k0==0 blocks).  Wq tile already in LDS.
// ---------------------------------------------------------------------------
__global__ __launch_bounds__(256) void split_wT(
    const float* __restrict__ Wq, const float* __restrict__ Wk,
    const float* __restrict__ Wv, const float* __restrict__ bq,
    const float* __restrict__ xsum,
    unsigned short* __restrict__ Bt, float* __restrict__ qg)
{
  int z = blockIdx.z;
  const float* W = (z == 0) ? Wq : (z == 1) ? Wk : Wv;
  __shared__ float tile[32][33];
  int t = threadIdx.x;
  int tx = t & 31, ty = t >> 5;                    // ty 0..7
  int k0 = blockIdx.x * 32, n0 = blockIdx.y * 32;
  #pragma unroll
  for (int i = 0; i < 4; ++i)
    tile[ty + i*8][tx] = W[(size_t)(k0 + ty + i*8) * 1024 + n0 + tx];
  __syncthreads();
  unsigned short* Bz = Bt + (size_t)z * 2097152;
  #pragma unroll
  for (int i = 0; i < 4; ++i) {
    int n = n0 + ty + i*8, kk = k0 + tx;
    float v = tile[tx][ty + i*8];
    unsigned short h = f2bf(v);
    Bz[(size_t)n * 2048 + kk]        = h;
    Bz[(size_t)n * 2048 + 1024 + kk] = f2bf(v - bf2f(h));
  }
  if (z == 0 && t < 128) {
    int n = t & 31, b = t >> 5;
    float dot = 0.f;
    #pragma unroll
    for (int kk = 0; kk < 32; ++kk)
      dot += xsum[b * E_ + k0 + kk] * tile[kk][n];
    float val = dot * (1.0f / (L_ * 8.0f));
    if (k0 == 0) val += bq[n0 + n] * 0.125f;
    atomicAdd(&qg[b * E_ + n0 + n], val);
  }
}

// ---------------------------------------------------------------------------
// Kernel 1: fused QKV, 256x256-tile / BK=64 / 8-wave, R5 schedule (best
// measured, 317.5 us): TWO raw s_barriers per K-tile + counted vmcnt.
//
// Grid: 768 blocks x 512 thr = 1 blk/CU (128 KiB LDS), exactly 3 rounds.
// XCD swizzle: xc = li&7; per-XCD order z-outer so one z's B matrix (4 MB)
// stays L2-resident while A streams.
//
// LDS (bytes): A0 [0,32K) A1 [32K,64K) B0 [64K,96K) B1 [96K,128K)
// tile = [256 rows][64 k] bf16, row = 128 B, 16B col-slot swizzled by
// slot ^= row&7 (inverse swizzle on global source, same XOR on ds_read, #21).
//
// Tile plan:
//   T1: LDA(0)+LDB(0)+LDB(1) [16 b128] -> lgkm0(own) -> MFMA Q(0,0),Q(0,1)
//   T2: LDA(1) [8 b128] -> BARR(#1) -> lgkm0 -> STAGE_B+STAGE_A(t+2)
//       -> MFMA Q(1,0),Q(1,1) -> vmcnt(8) -> BARR(#2)
// Ledger: prologue B0 A0 B1 A1 -> vmcnt(8) = tile0 landed; end-of-tile
// vmcnt(8) leaves exactly {B,A}(t+2) in flight; peeled tail drains vmcnt(0).
// CU-level model (R6): LDS pipe = 192 b128 reads + 64KB stage writes/tile is
// the throughput limit; further gains need read-redundancy reduction (parked).
//
// z==1 epilogue: wave tile = 128 rows x one head; logit = qg . k via 4-step
// fr-butterfly; aexp=exp(logit), denom += (fr==0 lanes).
// ---------------------------------------------------------------------------
#define PRIO1() __builtin_amdgcn_s_setprio(1)
#define PRIO0() __builtin_amdgcn_s_setprio(0)
#define BARR() do { asm volatile("" ::: "memory"); \
                    __builtin_amdgcn_s_barrier(); \
                    asm volatile("" ::: "memory"); } while (0)
#define WAITL0() asm volatile("s_waitcnt lgkmcnt(0)" ::: "memory")
#define WAITV(n) asm volatile("s_waitcnt vmcnt(" n ")" ::: "memory")

#define STAGE_A(buf, kofs) do { \
  const unsigned short* g_ = gA + (kofs); \
  char* d_ = dA0 + (buf) * 32768; \
  gload16(g_,          d_); \
  gload16(g_ + 131072, d_ +  8192); \
  gload16(g_ + 262144, d_ + 16384); \
  gload16(g_ + 393216, d_ + 24576); \
} while (0)

#define STAGE_B(buf, kofs) do { \
  const unsigned short* g_ = gB + (kofs); \
  char* d_ = dB0 + (buf) * 32768; \
  gload16(g_,          d_); \
  gload16(g_ + 131072, d_ +  8192); \
  gload16(g_ + 262144, d_ + 16384); \
  gload16(g_ + 393216, d_ + 24576); \
} while (0)

#define LDA(buf, mh) do { \
  const char* p_ = shb + (buf) * 32768 + arow + (mh) * 8192; \
  _Pragma("unroll") \
  for (int ii = 0; ii < 4; ++ii) { \
    aF[ii][0] = *(const s8*)(p_ + ii * 2048 + c0); \
    aF[ii][1] = *(const s8*)(p_ + ii * 2048 + c1); \
  } \
} while (0)

#define LDB(buf, nh) do { \
  const char* p_ = shb + 65536 + (buf) * 32768 + brow + (nh) * 4096; \
  _Pragma("unroll") \
  for (int jj = 0; jj < 2; ++jj) { \
    bF[(nh)*2+jj][0] = *(const s8*)(p_ + jj * 2048 + c0); \
    bF[(nh)*2+jj][1] = *(const s8*)(p_ + jj * 2048 + c1); \
  } \
} while (0)

#define MFMAQ(mh, nh) do { \
  _Pragma("unroll") \
  for (int ii = 0; ii < 4; ++ii) \
    _Pragma("unroll") \
    for (int jj = 0; jj < 2; ++jj) { \
      acc[(mh)*4+ii][(nh)*2+jj] = __builtin_amdgcn_mfma_f32_16x16x32_bf16( \
          aF[ii][0], bF[(nh)*2+jj][0], acc[(mh)*4+ii][(nh)*2+jj], 0, 0, 0); \
      acc[(mh)*4+ii][(nh)*2+jj] = __builtin_amdgcn_mfma_f32_16x16x32_bf16( \
          aF[ii][1], bF[(nh)*2+jj][1], acc[(mh)*4+ii][(nh)*2+jj], 0, 0, 0); \
    } \
} while (0)

// One K-tile in buffer `buf`, 2 barriers total; stages (if doStage) target
// tile kofs pair; vmN = vmcnt immediate (string) at tile end.
#define TILE2(buf, doStage, kB_, kA_, vmN) do { \
  /* T1: A-half0 + both B halves; own-wave wait; first 32 MFMA */ \
  LDA(buf, 0); LDB(buf, 0); LDB(buf, 1); \
  WAITL0(); \
  PRIO1(); MFMAQ(0, 0); MFMAQ(0, 1); PRIO0(); \
  /* T2: A-half1; WAR barrier; stages; last 32 MFMA; counted vmcnt; barrier */ \
  LDA(buf, 1); \
  BARR(); \
  WAITL0(); \
  if (doStage) { STAGE_B(buf, kB_); STAGE_A(buf, kA_); } \
  PRIO1(); MFMAQ(1, 0); MFMAQ(1, 1); PRIO0(); \
  WAITV(vmN); \
  BARR(); \
} while (0)

__global__ __launch_bounds__(512, 2) void qkv_mfma(
    const unsigned short* __restrict__ Ah, const unsigned short* __restrict__ Bt,
    const float* __restrict__ bq, const float* __restrict__ bk,
    const float* __restrict__ bv, const float* __restrict__ qg,
    float* __restrict__ aexp, float* __restrict__ denom,
    float* __restrict__ qo, float* __restrict__ ko, float* __restrict__ vo)
{
  __shared__ unsigned short sh[65536];   // 128 KiB

  const int t  = threadIdx.x;
  const int li = blockIdx.x;            // 0..767
  const int xc = li & 7;
  const int idx = li >> 3;              // 0..95 within XCD
  const int z   = idx >> 5;             // 0..2 (z-outer per XCD)
  const int rem = idx & 31;
  const int bm = (xc * 8 + (rem >> 2)) * 256;
  const int bn = (rem & 3) * 256;

  const float* bias = (z == 0) ? bq : (z == 1) ? bk : bv;
  float* out = (z == 0) ? qo : (z == 1) ? ko : vo;
  const unsigned short* Bz = Bt + (size_t)z * 2097152;

  // staging: thread t writes LDS bytes [region + t*16); physical (row,slot) =
  // (t>>3 + 64*ld, t&7).  Source column is the inverse-swizzled slot.
  const int srow = t >> 3;
  const int scol = ((t & 7) ^ (srow & 7)) * 8;        // elements
  const unsigned short* gA = Ah + (size_t)(bm + srow) * 2048 + scol;
  const unsigned short* gB = Bz + (size_t)(bn + srow) * 2048 + scol;
  char* const shb = (char*)sh;
  char* const dA0 = shb +         t * 16;
  char* const dB0 = shb + 65536 + t * 16;

  // compute mapping: 8 waves = 2M x 4N, wave tile 128x64
  const int lane = t & 63, wid = t >> 6;
  const int wm = wid >> 2, wn = wid & 3;
  const int fr = lane & 15, fq = lane >> 4;
  const int c0 = ((fq)     ^ (fr & 7)) * 16;          // kk=0 swizzled col byte
  const int c1 = ((fq + 4) ^ (fr & 7)) * 16;          // kk=1
  const int arow = (wm * 128 + fr) * 128;
  const int brow = (wn *  64 + fr) * 128;

  f4 acc[8][4] = {};
  s8 aF[4][2], bF[4][2];

  // prologue: tiles 0 (buf0) and 1 (buf1)
  STAGE_B(0, 0);  STAGE_A(0, 0);
  STAGE_B(1, 64); STAGE_A(1, 64);
  WAITV("8");
  BARR();

  // K' = 3072 = 48 tiles of 64; seg map: A cols [hi,hi,lo], B cols [hi,lo,hi]
  #pragma unroll 1
  for (int it = 0; it < 23; ++it) {
    const int t2 = 2 * it + 2, t3 = 2 * it + 3;
    const int kA2 = (t2 < 16) ? t2 * 64 : t2 * 64 - 1024;
    const int kB2 = (t2 < 32) ? t2 * 64 : t2 * 64 - 2048;
    const int kA3 = (t3 < 16) ? t3 * 64 : t3 * 64 - 1024;
    const int kB3 = (t3 < 32) ? t3 * 64 : t3 * 64 - 2048;
    TILE2(0, true, kB2, kA2, "8");
    TILE2(1, true, kB3, kA3, "8");
  }
  // peeled final iteration: tiles 46, 47 — no stages, drain
  TILE2(0, false, 0, 0, "0");
  TILE2(1, false, 0, 0, "0");

  // epilogue: C += bias, store
  float bv4[4];
  #pragma unroll
  for (int j = 0; j < 4; ++j) bv4[j] = bias[bn + wn * 64 + j * 16 + fr];
  #pragma unroll
  for (int i = 0; i < 8; ++i) {
    const int mrow = bm + wm * 128 + i * 16 + fq * 4;
    #pragma unroll
    for (int j = 0; j < 4; ++j) {
      const int ncol = bn + wn * 64 + j * 16 + fr;
      #pragma unroll
      for (int r = 0; r < 4; ++r)
        out[(size_t)(mrow + r) * E_ + ncol] = acc[i][j][r] + bv4[j];
    }
  }

  if (z == 1) {
    // alpha epilogue: this wave's 128 rows x head (bn>>6)+wn
    const int b_ = bm >> 12;
    const int h  = (bn >> 6) + wn;
    const int bh = b_ * 16 + h;
    float qgv[4];
    #pragma unroll
    for (int j = 0; j < 4; ++j) qgv[j] = qg[bh * 64 + j * 16 + fr];
    float partial[8][4];
    #pragma unroll
    for (int i = 0; i < 8; ++i)
      #pragma unroll
      for (int r = 0; r < 4; ++r) {
        float p = 0.f;
        #pragma unroll
        for (int j = 0; j < 4; ++j)
          p += qgv[j] * (acc[i][j][r] + bv4[j]);
        p += __shfl_xor(p, 1);
        p += __shfl_xor(p, 2);
        p += __shfl_xor(p, 4);
        p += __shfl_xor(p, 8);
        partial[i][r] = p;
      }
    if (fr == 0) {
      const int lbase = (bm & 4095) + wm * 128 + fq * 4;
      float s = 0.f;
      #pragma unroll
      for (int i = 0; i < 8; ++i)
        #pragma unroll
        for (int r = 0; r < 4; ++r) {
          float e = __expf(partial[i][r]);
          aexp[(size_t)bh * 4096 + lbase + i * 16 + r] = e;
          s += e;
        }
      atomicAdd(&denom[bh], s);
    }
  }
}

// ---------------------------------------------------------------------------
// Kernel 2 (R8): KV-state partials via MFMA, 48 KiB LDS -> 3 blocks/CU.
// R4's MFMA rewrite was neutral because 96 KiB forced 1 blk/CU (producer and
// MFMA phases fully serialized).  R8 fix: per block ONE 64-l sub-chunk buffer
// re-used twice (chunk = 128 l), acc carried in registers across sub-chunks.
// grid (64 bh, 32 chunks) -> 32 partials, state_reduce unchanged.
//
// Per sub-chunk:
//   producer (all 256 thr): thread = (l-pair, d-octet); load k,v (f32),
//     av=aexp*L/denom; gk=gfun(k*av), gmk=gfun(-k*av); split bf16 hi|lo;
//     write TRANSPOSED ushort2 {l0,l1} -> GT[64 d][128 c] (c: 0..63 hi,
//     64..127 lo), MT, VT.  16B-slot XOR swizzle: slot ^= d&7 (write+read
//     same XOR, in-kernel both sides).
//   sync -> MFMA sweep: 4 waves = (state s, d-half dh); K' = 3 segs x 64,
//     6 ksteps, 8 mfma_16x16x32_bf16 each (seg map A:[hi,hi,lo] B:[hi,lo,hi],
//     layouts verified in R4).  ksum rows summed from GT/MT by t<128.
//   sync (WAR) before next sub-chunk's writes; its global loads issue BEFORE
//   that sync -> HBM hides under current MFMA.
// ---------------------------------------------------------------------------
__global__ __launch_bounds__(256) void state_part(
    const float* __restrict__ k, const float* __restrict__ v,
    const float* __restrict__ aexp, const float* __restrict__ denom,
    float* __restrict__ Spart, float* __restrict__ SMpart,
    float* __restrict__ kpart, float* __restrict__ kmpart)
{
  __shared__ unsigned short lds[24576];   // GT[64][128] | MT | VT (48 KiB)
  const int bh = blockIdx.x, b = bh >> 4, h = bh & 15;
  const int c = blockIdx.y;               // 0..31
  const float scale = (float)L_ / denom[bh];
  const int t = threadIdx.x;

  const int wid = t >> 6, lane = t & 63;
  const int s = wid >> 1, dh = wid & 1;
  const int fr = lane & 15, fq = lane >> 4;
  const int lp = t >> 3, dg8 = (t & 7) * 8;   // producer role
  const int kd = t & 63, isM = (t >> 6) & 1;  // ksum role (t<128)
  const int kx7 = kd & 7;
  const unsigned short* AT = lds + s * 8192;  // GT (s=0) or MT (s=1)
  const unsigned short* VT = lds + 16384;

  f4 acc[2][4] = {};
  float ksr = 0.f;

  #pragma unroll 1
  for (int sc = 0; sc < 2; ++sc) {
    const int l0 = c * 128 + sc * 64 + 2 * lp;
    // global loads issue before the WAR sync (hide under prev MFMA)
    const size_t r0 = (size_t)(b * L_ + l0) * E_ + h * 64 + dg8;
    float4 kE0 = *(const float4*)(k + r0);
    float4 kE1 = *(const float4*)(k + r0 + 4);
    float4 kO0 = *(const float4*)(k + r0 + E_);
    float4 kO1 = *(const float4*)(k + r0 + E_ + 4);
    float4 vE0 = *(const float4*)(v + r0);
    float4 vE1 = *(const float4*)(v + r0 + 4);
    float4 vO0 = *(const float4*)(v + r0 + E_);
    float4 vO1 = *(const float4*)(v + r0 + E_ + 4);
    const float av0 = aexp[(size_t)bh * L_ + l0]     * scale;
    const float av1 = aexp[(size_t)bh * L_ + l0 + 1] * scale;
    const float ke[8] = {kE0.x,kE0.y,kE0.z,kE0.w,kE1.x,kE1.y,kE1.z,kE1.w};
    const float ko[8] = {kO0.x,kO0.y,kO0.z,kO0.w,kO1.x,kO1.y,kO1.z,kO1.w};
    const float ve[8] = {vE0.x,vE0.y,vE0.z,vE0.w,vE1.x,vE1.y,vE1.z,vE1.w};
    const float vo[8] = {vO0.x,vO0.y,vO0.z,vO0.w,vO1.x,vO1.y,vO1.z,vO1.w};
    if (sc) __syncthreads();   // WAR: prev sub-chunk fully read by all waves
    const int usl = 2 * lp;    // hi col; lo col = usl + 64
    #pragma unroll
    for (int j = 0; j < 8; ++j) {
      const int d = dg8 + j, x7 = d & 7;
      const int ph = d * 128 + (((usl >> 3)) ^ x7) * 8 + (usl & 7);
      const int pl = ph + 64;  // ((s+8)^x7) = (s^x7)+8 for x7<8
      const float ge = gfun( ke[j] * av0), go = gfun( ko[j] * av1);
      const float me = gfun(-ke[j] * av0), mo = gfun(-ko[j] * av1);
      unsigned short eh, oh;
      eh = f2bf(ge); oh = f2bf(go);
      *(unsigned int*)&lds[ph] = (unsigned)eh | ((unsigned)oh << 16);
      eh = f2bf(ge - bf2f(eh)); oh = f2bf(go - bf2f(oh));
      *(unsigned int*)&lds[pl] = (unsigned)eh | ((unsigned)oh << 16);
      eh = f2bf(me); oh = f2bf(mo);
      *(unsigned int*)&lds[8192 + ph] = (unsigned)eh | ((unsigned)oh << 16);
      eh = f2bf(me - bf2f(eh)); oh = f2bf(mo - bf2f(oh));
      *(unsigned int*)&lds[8192 + pl] = (unsigned)eh | ((unsigned)oh << 16);
      eh = f2bf(ve[j]); oh = f2bf(vo[j]);
      *(unsigned int*)&lds[16384 + ph] = (unsigned)eh | ((unsigned)oh << 16);
      eh = f2bf(ve[j] - bf2f(eh)); oh = f2bf(vo[j] - bf2f(oh));
      *(unsigned int*)&lds[16384 + pl] = (unsigned)eh | ((unsigned)oh << 16);
    }
    __syncthreads();
    // ---- MFMA sweep: K' = 3 segs x 64 cols, 6 ksteps ----
    #pragma unroll
    for (int ks = 0; ks < 6; ++ks) {
      const int seg = ks >> 1, loc = ks & 1;
      const int ac = loc * 32 + fq * 8 + ((seg == 2) ? 64 : 0);
      const int bc = loc * 32 + fq * 8 + ((seg == 1) ? 64 : 0);
      s8 aF[2], bF[4];
      #pragma unroll
      for (int m = 0; m < 2; ++m) {
        const int row = dh * 32 + m * 16 + fr;
        aF[m] = *(const s8*)&AT[row * 128 + ((ac >> 3) ^ (row & 7)) * 8];
      }
      #pragma unroll
      for (int n = 0; n < 4; ++n) {
        const int row = n * 16 + fr;
        bF[n] = *(const s8*)&VT[row * 128 + ((bc >> 3) ^ (row & 7)) * 8];
      }
      #pragma unroll
      for (int m = 0; m < 2; ++m)
        #pragma unroll
        for (int n = 0; n < 4; ++n)
          acc[m][n] = __builtin_amdgcn_mfma_f32_16x16x32_bf16(
              aF[m], bF[n], acc[m][n], 0, 0, 0);
    }
    // ---- ksum partial: row-sums of GT/MT (hi+lo) ----
    if (t < 128) {
      const unsigned short* R = lds + isM * 8192 + kd * 128;
      #pragma unroll
      for (int sl = 0; sl < 16; ++sl) {
        s8 w8 = *(const s8*)&R[(sl ^ kx7) * 8];
        #pragma unroll
        for (int e = 0; e < 8; ++e)
          ksr += bf2f((unsigned short)w8[e]);
      }
    }
  }

  float* Sp = (s == 0) ? Spart : SMpart;
  const size_t pb = ((size_t)(c * 64 + bh)) * 4096;
  #pragma unroll
  for (int m = 0; m < 2; ++m)
    #pragma unroll
    for (int n = 0; n < 4; ++n)
      #pragma unroll
      for (int r = 0; r < 4; ++r) {
        const int d  = dh * 32 + m * 16 + fq * 4 + r;
        const int vv = n * 16 + fr;
        Sp[pb + d * 64 + vv] = acc[m][n][r];
      }
  if (t < 128)
    (isM ? kmpart : kpart)[(c * 64 + bh) * 64 + kd] = ksr;
}

// ---------------------------------------------------------------------------
// Kernel 3: reduce 32 partials (deterministic).  grid (64 bh, 4 segs).
// ---------------------------------------------------------------------------
__global__ __launch_bounds__(256) void state_reduce(
    const float* __restrict__ Spart, const float* __restrict__ SMpart,
    const float* __restrict__ kpart, const float* __restrict__ kmpart,
    float* __restrict__ S, float* __restrict__ Sm,
    float* __restrict__ ksum, float* __restrict__ kmsum)
{
  int bh = blockIdx.x, seg = blockIdx.y, t = threadIdx.x;
  int idx = seg * 1024 + t * 4;
  float4 s = {0,0,0,0}, sm = {0,0,0,0};
  #pragma unroll
  for (int p = 0; p < 32; ++p) {
    float4 a = *(const float4*)&Spart [((size_t)(p*64 + bh))*4096 + idx];
    float4 c = *(const float4*)&SMpart[((size_t)(p*64 + bh))*4096 + idx];
    s.x += a.x; s.y += a.y; s.z += a.z; s.w += a.w;
    sm.x += c.x; sm.y += c.y; sm.z += c.z; sm.w += c.w;
  }
  *(float4*)&S [(size_t)bh*4096 + idx] = s;
  *(float4*)&Sm[(size_t)bh*4096 + idx] = sm;
  if (seg == 0 && t < 64) {
    float a = 0.f, c = 0.f;
    #pragma unroll
    for (int p = 0; p < 32; ++p) {
      a += kpart [(p*64 + bh)*64 + t];
      c += kmpart[(p*64 + bh)*64 + t];
    }
    ksum [bh*64 + t] = a;
    kmsum[bh*64 + t] = c;
  }
}

// ---------------------------------------------------------------------------
// Kernel 4 (R5 version — R7's 256-thr variant regressed via doubled S/Sm L1
// traffic): 128 threads, 16 l-groups x 8 v-groups, 4l x 8v tile.  S/Sm read
// from GLOBAL in-loop (L1-resident per bh); LDS only Gq/Gm (32 KB).
// ---------------------------------------------------------------------------
__global__ __launch_bounds__(128, 4) void out_kernel(
    const float* __restrict__ q,
    const float* __restrict__ S, const float* __restrict__ Sm,
    const float* __restrict__ ksum, const float* __restrict__ kmsum,
    float* __restrict__ out)
{
  int bh = blockIdx.x; int b = bh >> 4, h = bh & 15;
  int l0 = blockIdx.y * 64;
  __shared__ float Gq[64][64], Gm[64][64];   // [dd][l]
  int t = threadIdx.x;

  // q -> gfun -> transposed LDS.  lr=t>>1 (row), dq=(t&1)*32 (col half).
  int lr = t >> 1, dq = (t & 1) * 32;
  const float4* qp = (const float4*)(q + (size_t)(b*L_ + l0 + lr)*E_ + h*64 + dq);
  #pragma unroll
  for (int j = 0; j < 8; ++j) {
    float4 qv = qp[j];
    float vals[4] = {qv.x, qv.y, qv.z, qv.w};
    #pragma unroll
    for (int jj = 0; jj < 4; ++jj) {
      int dd = dq + j*4 + jj;
      Gq[dd][lr] = gfun(vals[jj]);
      Gm[dd][lr] = gfun(-vals[jj]);
    }
  }
  __syncthreads();

  int tn = (t & 7) * 8, tm = (t >> 3) * 4;
  const float* Sp   = S  + (size_t)bh*4096;
  const float* Smp  = Sm + (size_t)bh*4096;
  const float* ksp  = ksum  + bh*64;
  const float* kmsp = kmsum + bh*64;
  float acc[4][8] = {};
  float den[4] = {};
  #pragma unroll 2
  for (int kk = 0; kk < 64; ++kk) {
    float4 ga = *(const float4*)&Gq[kk][tm];
    float4 ma = *(const float4*)&Gm[kk][tm];
    float4 s0 = *(const float4*)&Sp [kk*64 + tn];
    float4 s1 = *(const float4*)&Sp [kk*64 + tn + 4];
    float4 m0 = *(const float4*)&Smp[kk*64 + tn];
    float4 m1 = *(const float4*)&Smp[kk*64 + tn + 4];
    float ksv = ksp[kk], kmv = kmsp[kk];
    float gv[4] = {ga.x, ga.y, ga.z, ga.w};
    float mv[4] = {ma.x, ma.y, ma.z, ma.w};
    float sv[8] = {s0.x, s0.y, s0.z, s0.w, s1.x, s1.y, s1.z, s1.w};
    float smv[8] = {m0.x, m0.y, m0.z, m0.w, m1.x, m1.y, m1.z, m1.w};
    #pragma unroll
    for (int i = 0; i < 4; ++i) {
      #pragma unroll
      for (int j = 0; j < 8; ++j)
        acc[i][j] += gv[i]*sv[j] + mv[i]*smv[j];
      den[i] += gv[i]*ksv + mv[i]*kmv;
    }
  }

  #pragma unroll
  for (int i = 0; i < 4; ++i) {
    float r = 1.0f / (den[i] + 1e-6f);
    float4 o0, o1;
    o0.x = acc[i][0]*r; o0.y = acc[i][1]*r; o0.z = acc[i][2]*r; o0.w = acc[i][3]*r;
    o1.x = acc[i][4]*r; o1.y = acc[i][5]*r; o1.z = acc[i][6]*r; o1.w = acc[i][7]*r;
    size_t ro = (size_t)(b*L_ + l0 + tm + i)*E_ + h*64 + tn;
    *(float4*)(out + ro)     = o0;
    *(float4*)(out + ro + 4) = o1;
  }
}

// ---------------------------------------------------------------------------
// Workspace layout (float units):
//   q      : 0          (+16,777,216)
//   k      : 16,777,216 (+16,777,216)
//   qg     : 33,554,432 (+4096)  \
//   denom  : 33,558,528 (+64)     | zeroed by one hipMemsetAsync (8256 fl)
//   xsum   : 33,558,592 (+4096)  /
//   S      : 33,562,688 (+262,144)
//   Sm     : 33,824,832 (+262,144)
//   ksum   : 34,086,976 (+4096)
//   kmsum  : 34,091,072 (+4096)
//   aexp   : 34,095,168 (+262,144)
//   Ah     : f-off 34,357,312 (ushort 33,554,432 = 16,777,216 fl)
//   Bt     : f-off 51,134,528 (ushort  6,291,456 =  3,145,728 fl)
//   end 54,280,256 fl = 217.1 MB
//   Overlays (dead after qkv_mfma): Spart @34,357,312 (+8,388,608),
//   SMpart @42,745,920 (+8,388,608) [= Ah region exactly], kpart @51,134,528
//   (+131,072), kmpart @51,265,600 (+131,072) [inside Bt region].
//   v lives in d_out (consumed by state_part, overwritten by out_kernel).
// ---------------------------------------------------------------------------
extern "C" void kernel_launch(void* const* d_in, const int* in_sizes, int n_in,
                              void* d_out, int out_size, void* d_ws, size_t ws_size,
                              hipStream_t stream) {
  const float* x  = (const float*)d_in[0];
  const float* Wq = (const float*)d_in[1];
  const float* bq = (const float*)d_in[2];
  const float* Wk = (const float*)d_in[3];
  const float* bk = (const float*)d_in[4];
  const float* Wv = (const float*)d_in[5];
  const float* bv = (const float*)d_in[6];
  float* out = (float*)d_out;
  float* ws  = (float*)d_ws;

  float* q      = ws;
  float* k      = ws + 16777216;
  float* qg     = ws + 33554432;
  float* denom  = ws + 33558528;
  float* xsum   = ws + 33558592;
  float* S      = ws + 33562688;
  float* Sm     = ws + 33824832;
  float* ksum   = ws + 34086976;
  float* kmsum  = ws + 34091072;
  float* aexp   = ws + 34095168;
  unsigned short* Ah = (unsigned short*)(ws + 34357312);
  unsigned short* Bt = (unsigned short*)(ws + 51134528);
  float* Spart  = ws + 34357312;   // overlays Ah (dead after qkv_mfma)
  float* SMpart = ws + 42745920;
  float* kpart  = ws + 51134528;   // overlays Bt (dead after qkv_mfma)
  float* kmpart = ws + 51265600;
  float* v      = out;

  hipMemsetAsync(qg, 0, 8256 * sizeof(float), stream);

  split_x<<<256, 256, 0, stream>>>(x, Ah, xsum);
  split_wT<<<dim3(32, 32, 3), 256, 0, stream>>>(Wq, Wk, Wv, bq, xsum, Bt, qg);
  qkv_mfma<<<dim3(768), 512, 0, stream>>>(Ah, Bt, bq, bk, bv, qg,
                                          aexp, denom, q, k, v);
  state_part<<<dim3(B_*H_, 32), 256, 0, stream>>>(k, v, aexp, denom,
                                                  Spart, SMpart, kpart, kmpart);
  state_reduce<<<dim3(B_*H_, 4), 256, 0, stream>>>(Spart, SMpart, kpart, kmpart,
                                                   S, Sm, ksum, kmsum);
  out_kernel<<<dim3(B_*H_, 64), 128, 0, stream>>>(q, S, Sm, ksum, kmsum, out);
}

// Round 9
// 544.352 us; speedup vs baseline: 1.2909x; 1.1398x over previous
//
#include <hip/hip_runtime.h>
#include <hip/hip_bf16.h>
#include <math.h>

// Problem constants
#define B_ 4
#define L_ 4096
#define E_ 1024
#define H_ 16
#define D_ 64
#define M_ (B_*L_)   // 16384 rows

typedef __attribute__((ext_vector_type(8))) short s8;     // 8 bf16 (4 VGPRs)
typedef __attribute__((ext_vector_type(4))) float f4;     // MFMA C/D

// g(x) = (softplus(5x)/5)^2 via HW v_exp/v_log; clamp z<=60 (no overflow).
__device__ __forceinline__ float gfun(float x) {
  float z = fminf(5.0f * x, 60.0f);
  float sp = 0.2f * __logf(1.0f + __expf(z));
  return sp * sp;
}

__device__ __forceinline__ unsigned short f2bf(float v) {
  __hip_bfloat16 h = __float2bfloat16(v);
  return *reinterpret_cast<unsigned short*>(&h);
}
__device__ __forceinline__ float bf2f(unsigned short u) {
  __hip_bfloat16 h = *reinterpret_cast<__hip_bfloat16*>(&u);
  return __bfloat162float(h);
}

// async global->LDS, 16 B per lane
__device__ __forceinline__ void gload16(const void* g, void* l) {
  __builtin_amdgcn_global_load_lds(
      (const __attribute__((address_space(1))) void*)g,
      (__attribute__((address_space(3))) void*)l, 16, 0, 0);
}

// ---------------------------------------------------------------------------
// Prep 1: split x into bf16 hi|lo -> Ah [16384,2048] + per-b column sums.
// grid 256 blocks x 256 thr; block = 64 rows of one b.
// ---------------------------------------------------------------------------
__global__ __launch_bounds__(256) void split_x(
    const float* __restrict__ x, unsigned short* __restrict__ Ah,
    float* __restrict__ xsum)
{
  int blk = blockIdx.x, t = threadIdx.x;
  int r0 = blk * 64, b = r0 >> 12;
  int c4 = t * 4;
  float4 cs = {0.f, 0.f, 0.f, 0.f};
  for (int r = 0; r < 64; ++r) {
    int row = r0 + r;
    float4 x4 = *(const float4*)(x + (size_t)row * E_ + c4);
    ushort4 hi, lo;
    unsigned short h;
    h = f2bf(x4.x); hi.x = h; lo.x = f2bf(x4.x - bf2f(h));
    h = f2bf(x4.y); hi.y = h; lo.y = f2bf(x4.y - bf2f(h));
    h = f2bf(x4.z); hi.z = h; lo.z = f2bf(x4.z - bf2f(h));
    h = f2bf(x4.w); hi.w = h; lo.w = f2bf(x4.w - bf2f(h));
    *(ushort4*)&Ah[(size_t)row * 2048 + c4]        = hi;
    *(ushort4*)&Ah[(size_t)row * 2048 + 1024 + c4] = lo;
    cs.x += x4.x; cs.y += x4.y; cs.z += x4.z; cs.w += x4.w;
  }
  atomicAdd(&xsum[b * E_ + c4 + 0], cs.x);
  atomicAdd(&xsum[b * E_ + c4 + 1], cs.y);
  atomicAdd(&xsum[b * E_ + c4 + 2], cs.z);
  atomicAdd(&xsum[b * E_ + c4 + 3], cs.w);
}

// ---------------------------------------------------------------------------
// Prep 2: transpose + split each W -> Bt[z] [1024,2048] bf16 (hi|lo).
// z==0 blocks also finish qg.
// ---------------------------------------------------------------------------
__global__ __launch_bounds__(256) void split_wT(
    const float* __restrict__ Wq, const float* __restrict__ Wk,
    const float* __restrict__ Wv, const float* __restrict__ bq,
    const float* __restrict__ xsum,
    unsigned short* __restrict__ Bt, float* __restrict__ qg)
{
  int z = blockIdx.z;
  const float* W = (z == 0) ? Wq : (z == 1) ? Wk : Wv;
  __shared__ float tile[32][33];
  int t = threadIdx.x;
  int tx = t & 31, ty = t >> 5;                    // ty 0..7
  int k0 = blockIdx.x * 32, n0 = blockIdx.y * 32;
  #pragma unroll
  for (int i = 0; i < 4; ++i)
    tile[ty + i*8][tx] = W[(size_t)(k0 + ty + i*8) * 1024 + n0 + tx];
  __syncthreads();
  unsigned short* Bz = Bt + (size_t)z * 2097152;
  #pragma unroll
  for (int i = 0; i < 4; ++i) {
    int n = n0 + ty + i*8, kk = k0 + tx;
    float v = tile[tx][ty + i*8];
    unsigned short h = f2bf(v);
    Bz[(size_t)n * 2048 + kk]        = h;
    Bz[(size_t)n * 2048 + 1024 + kk] = f2bf(v - bf2f(h));
  }
  if (z == 0 && t < 128) {
    int n = t & 31, b = t >> 5;
    float dot = 0.f;
    #pragma unroll
    for (int kk = 0; kk < 32; ++kk)
      dot += xsum[b * E_ + k0 + kk] * tile[kk][n];
    float val = dot * (1.0f / (L_ * 8.0f));
    if (k0 == 0) val += bq[n0 + n] * 0.125f;
    atomicAdd(&qg[b * E_ + n0 + n], val);
  }
}

// ---------------------------------------------------------------------------
// Kernel 1: fused QKV, 256x256-tile / BK=64 / 8-wave, R5 schedule (best
// measured): TWO raw s_barriers per K-tile + counted vmcnt.
// Grid: 768 x 512 thr = 1 blk/CU (128 KiB LDS).  XCD swizzle z-outer.
// LDS tile = [256 rows][64 k] bf16, 16B col-slot swizzled slot ^= row&7
// (inverse swizzle on global source, same XOR on ds_read, rule #21).
// Tile: T1 LDA(0)+LDB(0)+LDB(1) -> lgkm0 -> Q(0,0),Q(0,1);
//       T2 LDA(1) -> BARR -> lgkm0 -> stages(t+2) -> Q(1,0),Q(1,1)
//       -> vmcnt(8) -> BARR.  Peeled tail drains vmcnt(0).
// z==1 epilogue: alpha logits via fr-butterfly; aexp, denom.
// ---------------------------------------------------------------------------
#define PRIO1() __builtin_amdgcn_s_setprio(1)
#define PRIO0() __builtin_amdgcn_s_setprio(0)
#define BARR() do { asm volatile("" ::: "memory"); \
                    __builtin_amdgcn_s_barrier(); \
                    asm volatile("" ::: "memory"); } while (0)
#define WAITL0() asm volatile("s_waitcnt lgkmcnt(0)" ::: "memory")
#define WAITV(n) asm volatile("s_waitcnt vmcnt(" n ")" ::: "memory")

#define STAGE_A(buf, kofs) do { \
  const unsigned short* g_ = gA + (kofs); \
  char* d_ = dA0 + (buf) * 32768; \
  gload16(g_,          d_); \
  gload16(g_ + 131072, d_ +  8192); \
  gload16(g_ + 262144, d_ + 16384); \
  gload16(g_ + 393216, d_ + 24576); \
} while (0)

#define STAGE_B(buf, kofs) do { \
  const unsigned short* g_ = gB + (kofs); \
  char* d_ = dB0 + (buf) * 32768; \
  gload16(g_,          d_); \
  gload16(g_ + 131072, d_ +  8192); \
  gload16(g_ + 262144, d_ + 16384); \
  gload16(g_ + 393216, d_ + 24576); \
} while (0)

#define LDA(buf, mh) do { \
  const char* p_ = shb + (buf) * 32768 + arow + (mh) * 8192; \
  _Pragma("unroll") \
  for (int ii = 0; ii < 4; ++ii) { \
    aF[ii][0] = *(const s8*)(p_ + ii * 2048 + c0); \
    aF[ii][1] = *(const s8*)(p_ + ii * 2048 + c1); \
  } \
} while (0)

#define LDB(buf, nh) do { \
  const char* p_ = shb + 65536 + (buf) * 32768 + brow + (nh) * 4096; \
  _Pragma("unroll") \
  for (int jj = 0; jj < 2; ++jj) { \
    bF[(nh)*2+jj][0] = *(const s8*)(p_ + jj * 2048 + c0); \
    bF[(nh)*2+jj][1] = *(const s8*)(p_ + jj * 2048 + c1); \
  } \
} while (0)

#define MFMAQ(mh, nh) do { \
  _Pragma("unroll") \
  for (int ii = 0; ii < 4; ++ii) \
    _Pragma("unroll") \
    for (int jj = 0; jj < 2; ++jj) { \
      acc[(mh)*4+ii][(nh)*2+jj] = __builtin_amdgcn_mfma_f32_16x16x32_bf16( \
          aF[ii][0], bF[(nh)*2+jj][0], acc[(mh)*4+ii][(nh)*2+jj], 0, 0, 0); \
      acc[(mh)*4+ii][(nh)*2+jj] = __builtin_amdgcn_mfma_f32_16x16x32_bf16( \
          aF[ii][1], bF[(nh)*2+jj][1], acc[(mh)*4+ii][(nh)*2+jj], 0, 0, 0); \
    } \
} while (0)

#define TILE2(buf, doStage, kB_, kA_, vmN) do { \
  LDA(buf, 0); LDB(buf, 0); LDB(buf, 1); \
  WAITL0(); \
  PRIO1(); MFMAQ(0, 0); MFMAQ(0, 1); PRIO0(); \
  LDA(buf, 1); \
  BARR(); \
  WAITL0(); \
  if (doStage) { STAGE_B(buf, kB_); STAGE_A(buf, kA_); } \
  PRIO1(); MFMAQ(1, 0); MFMAQ(1, 1); PRIO0(); \
  WAITV(vmN); \
  BARR(); \
} while (0)

__global__ __launch_bounds__(512, 2) void qkv_mfma(
    const unsigned short* __restrict__ Ah, const unsigned short* __restrict__ Bt,
    const float* __restrict__ bq, const float* __restrict__ bk,
    const float* __restrict__ bv, const float* __restrict__ qg,
    float* __restrict__ aexp, float* __restrict__ denom,
    float* __restrict__ qo, float* __restrict__ ko, float* __restrict__ vo)
{
  __shared__ unsigned short sh[65536];   // 128 KiB

  const int t  = threadIdx.x;
  const int li = blockIdx.x;            // 0..767
  const int xc = li & 7;
  const int idx = li >> 3;              // 0..95 within XCD
  const int z   = idx >> 5;             // 0..2 (z-outer per XCD)
  const int rem = idx & 31;
  const int bm = (xc * 8 + (rem >> 2)) * 256;
  const int bn = (rem & 3) * 256;

  const float* bias = (z == 0) ? bq : (z == 1) ? bk : bv;
  float* out = (z == 0) ? qo : (z == 1) ? ko : vo;
  const unsigned short* Bz = Bt + (size_t)z * 2097152;

  const int srow = t >> 3;
  const int scol = ((t & 7) ^ (srow & 7)) * 8;        // elements
  const unsigned short* gA = Ah + (size_t)(bm + srow) * 2048 + scol;
  const unsigned short* gB = Bz + (size_t)(bn + srow) * 2048 + scol;
  char* const shb = (char*)sh;
  char* const dA0 = shb +         t * 16;
  char* const dB0 = shb + 65536 + t * 16;

  const int lane = t & 63, wid = t >> 6;
  const int wm = wid >> 2, wn = wid & 3;
  const int fr = lane & 15, fq = lane >> 4;
  const int c0 = ((fq)     ^ (fr & 7)) * 16;          // kk=0 swizzled col byte
  const int c1 = ((fq + 4) ^ (fr & 7)) * 16;          // kk=1
  const int arow = (wm * 128 + fr) * 128;
  const int brow = (wn *  64 + fr) * 128;

  f4 acc[8][4] = {};
  s8 aF[4][2], bF[4][2];

  // prologue: tiles 0 (buf0) and 1 (buf1)
  STAGE_B(0, 0);  STAGE_A(0, 0);
  STAGE_B(1, 64); STAGE_A(1, 64);
  WAITV("8");
  BARR();

  // K' = 3072 = 48 tiles of 64; seg map: A cols [hi,hi,lo], B cols [hi,lo,hi]
  #pragma unroll 1
  for (int it = 0; it < 23; ++it) {
    const int t2 = 2 * it + 2, t3 = 2 * it + 3;
    const int kA2 = (t2 < 16) ? t2 * 64 : t2 * 64 - 1024;
    const int kB2 = (t2 < 32) ? t2 * 64 : t2 * 64 - 2048;
    const int kA3 = (t3 < 16) ? t3 * 64 : t3 * 64 - 1024;
    const int kB3 = (t3 < 32) ? t3 * 64 : t3 * 64 - 2048;
    TILE2(0, true, kB2, kA2, "8");
    TILE2(1, true, kB3, kA3, "8");
  }
  // peeled final iteration: tiles 46, 47 — no stages, drain
  TILE2(0, false, 0, 0, "0");
  TILE2(1, false, 0, 0, "0");

  // epilogue: C += bias, store
  float bv4[4];
  #pragma unroll
  for (int j = 0; j < 4; ++j) bv4[j] = bias[bn + wn * 64 + j * 16 + fr];
  #pragma unroll
  for (int i = 0; i < 8; ++i) {
    const int mrow = bm + wm * 128 + i * 16 + fq * 4;
    #pragma unroll
    for (int j = 0; j < 4; ++j) {
      const int ncol = bn + wn * 64 + j * 16 + fr;
      #pragma unroll
      for (int r = 0; r < 4; ++r)
        out[(size_t)(mrow + r) * E_ + ncol] = acc[i][j][r] + bv4[j];
    }
  }

  if (z == 1) {
    const int b_ = bm >> 12;
    const int h  = (bn >> 6) + wn;
    const int bh = b_ * 16 + h;
    float qgv[4];
    #pragma unroll
    for (int j = 0; j < 4; ++j) qgv[j] = qg[bh * 64 + j * 16 + fr];
    float partial[8][4];
    #pragma unroll
    for (int i = 0; i < 8; ++i)
      #pragma unroll
      for (int r = 0; r < 4; ++r) {
        float p = 0.f;
        #pragma unroll
        for (int j = 0; j < 4; ++j)
          p += qgv[j] * (acc[i][j][r] + bv4[j]);
        p += __shfl_xor(p, 1);
        p += __shfl_xor(p, 2);
        p += __shfl_xor(p, 4);
        p += __shfl_xor(p, 8);
        partial[i][r] = p;
      }
    if (fr == 0) {
      const int lbase = (bm & 4095) + wm * 128 + fq * 4;
      float s = 0.f;
      #pragma unroll
      for (int i = 0; i < 8; ++i)
        #pragma unroll
        for (int r = 0; r < 4; ++r) {
          float e = __expf(partial[i][r]);
          aexp[(size_t)bh * 4096 + lbase + i * 16 + r] = e;
          s += e;
        }
      atomicAdd(&denom[bh], s);
    }
  }
}

// ---------------------------------------------------------------------------
// Kernel 2 (R8, measured good): KV-state partials via MFMA, 48 KiB LDS ->
// 3 blocks/CU.  Per block one 64-l sub-chunk buffer re-used twice; acc in
// registers across sub-chunks.  grid (64 bh, 32 chunks) -> 32 partials.
// ---------------------------------------------------------------------------
__global__ __launch_bounds__(256) void state_part(
    const float* __restrict__ k, const float* __restrict__ v,
    const float* __restrict__ aexp, const float* __restrict__ denom,
    float* __restrict__ Spart, float* __restrict__ SMpart,
    float* __restrict__ kpart, float* __restrict__ kmpart)
{
  __shared__ unsigned short lds[24576];   // GT[64][128] | MT | VT (48 KiB)
  const int bh = blockIdx.x, b = bh >> 4, h = bh & 15;
  const int c = blockIdx.y;               // 0..31
  const float scale = (float)L_ / denom[bh];
  const int t = threadIdx.x;

  const int wid = t >> 6, lane = t & 63;
  const int s = wid >> 1, dh = wid & 1;
  const int fr = lane & 15, fq = lane >> 4;
  const int lp = t >> 3, dg8 = (t & 7) * 8;   // producer role
  const int kd = t & 63, isM = (t >> 6) & 1;  // ksum role (t<128)
  const int kx7 = kd & 7;
  const unsigned short* AT = lds + s * 8192;  // GT (s=0) or MT (s=1)
  const unsigned short* VT = lds + 16384;

  f4 acc[2][4] = {};
  float ksr = 0.f;

  #pragma unroll 1
  for (int sc = 0; sc < 2; ++sc) {
    const int l0 = c * 128 + sc * 64 + 2 * lp;
    const size_t r0 = (size_t)(b * L_ + l0) * E_ + h * 64 + dg8;
    float4 kE0 = *(const float4*)(k + r0);
    float4 kE1 = *(const float4*)(k + r0 + 4);
    float4 kO0 = *(const float4*)(k + r0 + E_);
    float4 kO1 = *(const float4*)(k + r0 + E_ + 4);
    float4 vE0 = *(const float4*)(v + r0);
    float4 vE1 = *(const float4*)(v + r0 + 4);
    float4 vO0 = *(const float4*)(v + r0 + E_);
    float4 vO1 = *(const float4*)(v + r0 + E_ + 4);
    const float av0 = aexp[(size_t)bh * L_ + l0]     * scale;
    const float av1 = aexp[(size_t)bh * L_ + l0 + 1] * scale;
    const float ke[8] = {kE0.x,kE0.y,kE0.z,kE0.w,kE1.x,kE1.y,kE1.z,kE1.w};
    const float ko[8] = {kO0.x,kO0.y,kO0.z,kO0.w,kO1.x,kO1.y,kO1.z,kO1.w};
    const float ve[8] = {vE0.x,vE0.y,vE0.z,vE0.w,vE1.x,vE1.y,vE1.z,vE1.w};
    const float vo[8] = {vO0.x,vO0.y,vO0.z,vO0.w,vO1.x,vO1.y,vO1.z,vO1.w};
    if (sc) __syncthreads();   // WAR: prev sub-chunk fully read by all waves
    const int usl = 2 * lp;    // hi col; lo col = usl + 64
    #pragma unroll
    for (int j = 0; j < 8; ++j) {
      const int d = dg8 + j, x7 = d & 7;
      const int ph = d * 128 + (((usl >> 3)) ^ x7) * 8 + (usl & 7);
      const int pl = ph + 64;
      const float ge = gfun( ke[j] * av0), go = gfun( ko[j] * av1);
      const float me = gfun(-ke[j] * av0), mo = gfun(-ko[j] * av1);
      unsigned short eh, oh;
      eh = f2bf(ge); oh = f2bf(go);
      *(unsigned int*)&lds[ph] = (unsigned)eh | ((unsigned)oh << 16);
      eh = f2bf(ge - bf2f(eh)); oh = f2bf(go - bf2f(oh));
      *(unsigned int*)&lds[pl] = (unsigned)eh | ((unsigned)oh << 16);
      eh = f2bf(me); oh = f2bf(mo);
      *(unsigned int*)&lds[8192 + ph] = (unsigned)eh | ((unsigned)oh << 16);
      eh = f2bf(me - bf2f(eh)); oh = f2bf(mo - bf2f(oh));
      *(unsigned int*)&lds[8192 + pl] = (unsigned)eh | ((unsigned)oh << 16);
      eh = f2bf(ve[j]); oh = f2bf(vo[j]);
      *(unsigned int*)&lds[16384 + ph] = (unsigned)eh | ((unsigned)oh << 16);
      eh = f2bf(ve[j] - bf2f(eh)); oh = f2bf(vo[j] - bf2f(oh));
      *(unsigned int*)&lds[16384 + pl] = (unsigned)eh | ((unsigned)oh << 16);
    }
    __syncthreads();
    // ---- MFMA sweep: K' = 3 segs x 64 cols, 6 ksteps ----
    #pragma unroll
    for (int ks = 0; ks < 6; ++ks) {
      const int seg = ks >> 1, loc = ks & 1;
      const int ac = loc * 32 + fq * 8 + ((seg == 2) ? 64 : 0);
      const int bc = loc * 32 + fq * 8 + ((seg == 1) ? 64 : 0);
      s8 aF[2], bF[4];
      #pragma unroll
      for (int m = 0; m < 2; ++m) {
        const int row = dh * 32 + m * 16 + fr;
        aF[m] = *(const s8*)&AT[row * 128 + ((ac >> 3) ^ (row & 7)) * 8];
      }
      #pragma unroll
      for (int n = 0; n < 4; ++n) {
        const int row = n * 16 + fr;
        bF[n] = *(const s8*)&VT[row * 128 + ((bc >> 3) ^ (row & 7)) * 8];
      }
      #pragma unroll
      for (int m = 0; m < 2; ++m)
        #pragma unroll
        for (int n = 0; n < 4; ++n)
          acc[m][n] = __builtin_amdgcn_mfma_f32_16x16x32_bf16(
              aF[m], bF[n], acc[m][n], 0, 0, 0);
    }
    // ---- ksum partial: row-sums of GT/MT (hi+lo) ----
    if (t < 128) {
      const unsigned short* R = lds + isM * 8192 + kd * 128;
      #pragma unroll
      for (int sl = 0; sl < 16; ++sl) {
        s8 w8 = *(const s8*)&R[(sl ^ kx7) * 8];
        #pragma unroll
        for (int e = 0; e < 8; ++e)
          ksr += bf2f((unsigned short)w8[e]);
      }
    }
  }

  float* Sp = (s == 0) ? Spart : SMpart;
  const size_t pb = ((size_t)(c * 64 + bh)) * 4096;
  #pragma unroll
  for (int m = 0; m < 2; ++m)
    #pragma unroll
    for (int n = 0; n < 4; ++n)
      #pragma unroll
      for (int r = 0; r < 4; ++r) {
        const int d  = dh * 32 + m * 16 + fq * 4 + r;
        const int vv = n * 16 + fr;
        Sp[pb + d * 64 + vv] = acc[m][n][r];
      }
  if (t < 128)
    (isM ? kmpart : kpart)[(c * 64 + bh) * 64 + kd] = ksr;
}

// ---------------------------------------------------------------------------
// Kernel 3 (R9): reduce 32 partials AND emit the out-kernel B-operand:
// SBT[bh][80][256] bf16 (LINEAR, unswizzled):
//   rows 0..63 (vv): k 0..63 = hi(S^T), 64..127 = lo(S^T),
//                    128..191 = hi(Sm^T), 192..255 = lo(Sm^T)
//   row 64: ksum hi|lo, kmsum hi|lo (den as a 5th MFMA n-fragment)
//   rows 65..79: zero.
// grid (64 bh, 4 segs of 16 d-rows), 256 thr.
// ---------------------------------------------------------------------------
__global__ __launch_bounds__(256) void state_reduce(
    const float* __restrict__ Spart, const float* __restrict__ SMpart,
    const float* __restrict__ kpart, const float* __restrict__ kmpart,
    unsigned short* __restrict__ SBT)
{
  int bh = blockIdx.x, seg = blockIdx.y, t = threadIdx.x;
  int idx = seg * 1024 + t * 4;
  int d = idx >> 6, vv = idx & 63;
  float4 s = {0,0,0,0}, sm = {0,0,0,0};
  #pragma unroll
  for (int p = 0; p < 32; ++p) {
    float4 a = *(const float4*)&Spart [((size_t)(p*64 + bh))*4096 + idx];
    float4 c = *(const float4*)&SMpart[((size_t)(p*64 + bh))*4096 + idx];
    s.x += a.x; s.y += a.y; s.z += a.z; s.w += a.w;
    sm.x += c.x; sm.y += c.y; sm.z += c.z; sm.w += c.w;
  }
  unsigned short* SB = SBT + (size_t)bh * 20480;
  const float sa[4] = {s.x, s.y, s.z, s.w};
  const float sb[4] = {sm.x, sm.y, sm.z, sm.w};
  #pragma unroll
  for (int j = 0; j < 4; ++j) {
    unsigned short h1 = f2bf(sa[j]);
    SB[(vv + j) * 256 + d]       = h1;
    SB[(vv + j) * 256 + 64 + d]  = f2bf(sa[j] - bf2f(h1));
    unsigned short h2 = f2bf(sb[j]);
    SB[(vv + j) * 256 + 128 + d] = h2;
    SB[(vv + j) * 256 + 192 + d] = f2bf(sb[j] - bf2f(h2));
  }
  if (seg == 0) {
    if (t < 64) {
      float a = 0.f, c = 0.f;
      #pragma unroll
      for (int p = 0; p < 32; ++p) {
        a += kpart [(p*64 + bh)*64 + t];
        c += kmpart[(p*64 + bh)*64 + t];
      }
      unsigned short h = f2bf(a);
      SB[64*256 + t]       = h;
      SB[64*256 + 64 + t]  = f2bf(a - bf2f(h));
      h = f2bf(c);
      SB[64*256 + 128 + t] = h;
      SB[64*256 + 192 + t] = f2bf(c - bf2f(h));
    }
    for (int i = t; i < 15 * 256; i += 256)
      SB[65*256 + i] = 0;
  }
}

// ---------------------------------------------------------------------------
// Kernel 4 (R9 rewrite): output via MFMA (was VALU, 55us FLOP floor +
// L1-bound S/Sm re-reads).  grid (64 bh, 64 l-blocks), 256 thr, 72 KiB LDS
// -> 2 blocks/CU.
//   LDS: A GT[64 l][256 k] @0 (gq/gm split: k 0..63 gq-hi, 64..127 gq-lo,
//        128..191 gm-hi, 192..255 gm-lo), B BT[80 n][256 k] @32768 (from
//        SBT).  Both use 16B-slot XOR swizzle slot ^= row&7; B staged via
//        gload16 with inverse-swizzled GLOBAL source (rule #21).
//   MFMA: 4 waves = m-frags (16 l each); 12 ksteps = 2 states x 3 segs x
//   2 locs, seg map A:[hi,hi,lo] x B:[hi,lo,hi]; 5 n-frags (4 out cols +
//   den via SBT row 64).  den broadcast: __shfl(acc4, lane&48).
// ---------------------------------------------------------------------------
__global__ __launch_bounds__(256, 2) void out_kernel(
    const float* __restrict__ q, const unsigned short* __restrict__ SBT,
    float* __restrict__ out)
{
  __shared__ unsigned short lds[36864];   // 72 KiB: A 32K | B 40K
  const int bh = blockIdx.x, b = bh >> 4, h = bh & 15;
  const int l0 = blockIdx.y * 64;
  const int t = threadIdx.x;
  char* const shb = (char*)lds;

  // ---- stage B: SBT[bh] -> LDS (linear dest + inverse-swz source) ----
  {
    const unsigned short* SBg = SBT + (size_t)bh * 20480;
    const int sl = t & 31, rb = t >> 5;
    const unsigned short* src = SBg + rb * 256 + ((sl ^ (rb & 7)) * 8);
    char* dst = shb + 32768 + t * 16;
    #pragma unroll
    for (int i = 0; i < 10; ++i)
      gload16(src + i * 2048, dst + (size_t)i * 4096);
  }

  // ---- producer: q -> gfun -> split -> A region (swizzled ds_writes) ----
  {
    const int lr = t >> 2, dq = (t & 3) * 16;
    const float* qrow = q + (size_t)(b * L_ + l0 + lr) * E_ + h * 64 + dq;
    float qv[16];
    #pragma unroll
    for (int i = 0; i < 4; ++i) {
      float4 x = *(const float4*)(qrow + i * 4);
      qv[i*4+0] = x.x; qv[i*4+1] = x.y; qv[i*4+2] = x.z; qv[i*4+3] = x.w;
    }
    const int x7 = lr & 7;
    #pragma unroll
    for (int oct = 0; oct < 2; ++oct) {
      const int sb = (dq >> 3) + oct;       // logical 16B slot within hi-range
      s8 ghi, glo, mhi, mlo;
      #pragma unroll
      for (int j = 0; j < 8; ++j) {
        float qx = qv[oct * 8 + j];
        float g = gfun(qx);
        unsigned short gh = f2bf(g);
        ghi[j] = (short)gh;
        glo[j] = (short)f2bf(g - bf2f(gh));
        float m = gfun(-qx);
        unsigned short mh = f2bf(m);
        mhi[j] = (short)mh;
        mlo[j] = (short)f2bf(m - bf2f(mh));
      }
      char* base = shb + lr * 512 + ((sb ^ x7) * 16);
      *(s8*)(base)        = ghi;            // slots 0..7   (gq hi)
      *(s8*)(base + 128)  = glo;            // slots 8..15  (gq lo)
      *(s8*)(base + 256)  = mhi;            // slots 16..23 (gm hi)
      *(s8*)(base + 384)  = mlo;            // slots 24..31 (gm lo)
    }
  }
  WAITV("0");
  __syncthreads();

  // ---- MFMA sweep ----
  const int wid = t >> 6, lane = t & 63;
  const int fr = lane & 15, fq = lane >> 4;
  const int arow = wid * 16 + fr;
  const int ax7 = fr & 7;                   // arow&7 (wid*16 = 0 mod 8)
  f4 acc[5] = {{0.f,0.f,0.f,0.f},{0.f,0.f,0.f,0.f},{0.f,0.f,0.f,0.f},
               {0.f,0.f,0.f,0.f},{0.f,0.f,0.f,0.f}};
  #pragma unroll
  for (int ks = 0; ks < 12; ++ks) {
    const int st = ks / 6, rm = ks % 6, sg = rm >> 1, lc = rm & 1;
    const int acol = st * 128 + ((sg == 2) ? 64 : 0) + lc * 32 + fq * 8;
    const int bcol = st * 128 + ((sg == 1) ? 64 : 0) + lc * 32 + fq * 8;
    s8 aF = *(const s8*)(shb + arow * 512 + (((acol >> 3) ^ ax7) * 16));
    s8 bF[5];
    #pragma unroll
    for (int n = 0; n < 5; ++n) {
      const int brow = n * 16 + fr;
      bF[n] = *(const s8*)(shb + 32768 + brow * 512 +
                           (((bcol >> 3) ^ (brow & 7)) * 16));
    }
    #pragma unroll
    for (int n = 0; n < 5; ++n)
      acc[n] = __builtin_amdgcn_mfma_f32_16x16x32_bf16(aF, bF[n], acc[n], 0, 0, 0);
  }

  // ---- epilogue: den broadcast + store ----
  float rden[4];
  #pragma unroll
  for (int r = 0; r < 4; ++r) {
    float dsum = __shfl(acc[4][r], lane & 48);   // from (fq, fr=0)
    rden[r] = 1.0f / (dsum + 1e-6f);
  }
  #pragma unroll
  for (int n = 0; n < 4; ++n) {
    const int col = h * 64 + n * 16 + fr;
    #pragma unroll
    for (int r = 0; r < 4; ++r) {
      const size_t row = (size_t)(b * L_ + l0 + wid * 16 + fq * 4 + r);
      out[row * E_ + col] = acc[n][r] * rden[r];
    }
  }
}

// ---------------------------------------------------------------------------
// Workspace layout (float units):
//   q      : 0          (+16,777,216)
//   k      : 16,777,216 (+16,777,216)
//   qg     : 33,554,432 (+4096)  \
//   denom  : 33,558,528 (+64)     | zeroed by one hipMemsetAsync (8256 fl)
//   xsum   : 33,558,592 (+4096)  /
//   SBT    : 33,562,688 (ushort 1,310,720 = 655,360 fl) [R9: replaces
//            S/Sm/ksum/kmsum; overlays dead aexp tail region too]
//   aexp   : 34,095,168 (+262,144)  [dead after state_part; SBT overlays]
//   Ah     : f-off 34,357,312 (ushort 33,554,432 = 16,777,216 fl)
//   Bt     : f-off 51,134,528 (ushort  6,291,456 =  3,145,728 fl)
//   Overlays (dead after qkv_mfma): Spart @34,357,312 (+8,388,608),
//   SMpart @42,745,920 (+8,388,608), kpart @51,134,528 (+131,072),
//   kmpart @51,265,600 (+131,072).
//   v lives in d_out (consumed by state_part, overwritten by out_kernel).
//   Order: state_part reads aexp -> state_reduce writes SBT (aexp dead) ->
//   out_kernel reads SBT + q.
// ---------------------------------------------------------------------------
extern "C" void kernel_launch(void* const* d_in, const int* in_sizes, int n_in,
                              void* d_out, int out_size, void* d_ws, size_t ws_size,
                              hipStream_t stream) {
  const float* x  = (const float*)d_in[0];
  const float* Wq = (const float*)d_in[1];
  const float* bq = (const float*)d_in[2];
  const float* Wk = (const float*)d_in[3];
  const float* bk = (const float*)d_in[4];
  const float* Wv = (const float*)d_in[5];
  const float* bv = (const float*)d_in[6];
  float* out = (float*)d_out;
  float* ws  = (float*)d_ws;

  float* q      = ws;
  float* k      = ws + 16777216;
  float* qg     = ws + 33554432;
  float* denom  = ws + 33558528;
  float* xsum   = ws + 33558592;
  unsigned short* SBT = (unsigned short*)(ws + 33562688);
  float* aexp   = ws + 34095168;
  unsigned short* Ah = (unsigned short*)(ws + 34357312);
  unsigned short* Bt = (unsigned short*)(ws + 51134528);
  float* Spart  = ws + 34357312;   // overlays Ah (dead after qkv_mfma)
  float* SMpart = ws + 42745920;
  float* kpart  = ws + 51134528;   // overlays Bt (dead after qkv_mfma)
  float* kmpart = ws + 51265600;
  float* v      = out;

  hipMemsetAsync(qg, 0, 8256 * sizeof(float), stream);

  split_x<<<256, 256, 0, stream>>>(x, Ah, xsum);
  split_wT<<<dim3(32, 32, 3), 256, 0, stream>>>(Wq, Wk, Wv, bq, xsum, Bt, qg);
  qkv_mfma<<<dim3(768), 512, 0, stream>>>(Ah, Bt, bq, bk, bv, qg,
                                          aexp, denom, q, k, v);
  state_part<<<dim3(B_*H_, 32), 256, 0, stream>>>(k, v, aexp, denom,
                                                  Spart, SMpart, kpart, kmpart);
  state_reduce<<<dim3(B_*H_, 4), 256, 0, stream>>>(Spart, SMpart, kpart, kmpart,
                                                   SBT);
  out_kernel<<<dim3(B_*H_, 64), 256, 0, stream>>>(q, SBT, out);
}